// Round 6
// baseline (1792.487 us; speedup 1.0000x reference)
//
#include <hip/hip_runtime.h>
#include <hip/hip_fp16.h>

// ---------------------------------------------------------------------------
// GNN traffic predictor: embed -> GCNConv x2 -> edge MLP
// N=100000, E=1600000, F_NODE=32, F_EDGE=8, H=64
// Round 6: drop fine CSR (fill_csr was write-amp bound: 107MB HBM writes for
// a 6.4MB array). Coarse 128-node buckets via LDS counting sort (rank-
// clustered writes), conv = bucket-local LDS f32 accumulation with ds_add_f32
// + fused self-loop/bias/relu epilogue. Hh pre-scaled by dinv[src] in lin.
// ---------------------------------------------------------------------------

typedef __attribute__((ext_vector_type(8))) _Float16 half8;
typedef __attribute__((ext_vector_type(4))) float f32x4;

__device__ __forceinline__ unsigned short f2h(float f) {
    return __half_as_ushort(__float2half(f));
}
__device__ __forceinline__ float h2f(unsigned short u) {
    return __half2float(__ushort_as_half(u));
}

#define RB 128           // nodes per bucket
#define NBKT 782         // ceil(100000/128); recomputed at launch
#define BINCHUNK 4096    // edges per bin_k block

// ---- index dtype detection: flag=1 -> int32, 0 -> int64 --------------------
__global__ void detect_idx_k(const unsigned int* __restrict__ ei, int* __restrict__ flag) {
    int nz = 0;
    for (int i = threadIdx.x; i < 2048; i += 64)
        if (ei[2 * i + 1] != 0u) nz = 1;
    unsigned long long m = __ballot(nz);
    if (threadIdx.x == 0) *flag = (m != 0ull) ? 1 : 0;
}

// ---- fused index convert + degree count ------------------------------------
__global__ void cvt_deg_k(const void* __restrict__ ei, const int* __restrict__ flag,
                          int* __restrict__ out, int* __restrict__ deg, int E) {
    int i = blockIdx.x * 256 + threadIdx.x;
    if (i >= 2 * E) return;
    int v;
    if (*flag) v = ((const int*)ei)[i];
    else       v = (int)((const long long*)ei)[i];
    out[i] = v;
    if (i >= E) atomicAdd(&deg[v], 1);  // dst half
}

// ---- rowptr scan -----------------------------------------------------------
__global__ void scan_blk_k(const int* __restrict__ deg, int* __restrict__ part,
                           int* __restrict__ bsum, int n1) {
    __shared__ int s[256];
    int t = threadIdx.x;
    int i = blockIdx.x * 256 + t;
    int v = (i < n1) ? deg[i] : 0;
    s[t] = v;
    __syncthreads();
    for (int o = 1; o < 256; o <<= 1) {
        int x = (t >= o) ? s[t - o] : 0;
        __syncthreads();
        s[t] += x;
        __syncthreads();
    }
    if (i < n1) part[i] = s[t] - v;  // exclusive
    if (t == 255) bsum[blockIdx.x] = s[255];
}

__global__ void scan_tot_k(int* __restrict__ bsum, int nb) {
    __shared__ int s[512];
    int t = threadIdx.x;
    int v = (t < nb) ? bsum[t] : 0;
    s[t] = v;
    __syncthreads();
    for (int o = 1; o < 512; o <<= 1) {
        int x = (t >= o) ? s[t - o] : 0;
        __syncthreads();
        s[t] += x;
        __syncthreads();
    }
    if (t < nb) bsum[t] = s[t] - v;
}

__global__ void scan_add_k(const int* __restrict__ part, const int* __restrict__ bsum,
                           int* __restrict__ rowptr, int n1) {
    int i = blockIdx.x * 256 + threadIdx.x;
    if (i < n1) rowptr[i] = part[i] + bsum[blockIdx.x];
}

__global__ void dinv_k(const int* __restrict__ deg, float* __restrict__ dinv, int n) {
    int i = blockIdx.x * 256 + threadIdx.x;
    if (i < n) dinv[i] = rsqrtf((float)deg[i] + 1.0f);  // +1 self-loop
}

__global__ void bcur_init_k(const int* __restrict__ rowptr, int* __restrict__ bcur,
                            int nbkt) {
    int b = blockIdx.x * 256 + threadIdx.x;
    if (b < nbkt) bcur[b] = rowptr[b * RB];
}

// ---- bucket binning: pairB[slot] = src | (dst&127)<<20, grouped by dst>>7 --
// LDS counting sort gives rank-clustered writes (vs round-5 fill_csr's
// isolated 4B scatters costing a 64B line each -> 107MB HBM writes).
__global__ __launch_bounds__(256) void bin_k(
    const int* __restrict__ src, const int* __restrict__ dst,
    int* __restrict__ bcur, unsigned int* __restrict__ pairB, int E, int nbkt) {
    __shared__ int lsrc[BINCHUNK];
    __shared__ int ldst[BINCHUNK];
    __shared__ int cnt[NBKT], gbase[NBKT];
    int t = threadIdx.x;
    int base = blockIdx.x * BINCHUNK;
    int n = E - base; if (n > BINCHUNK) n = BINCHUNK;
    for (int i = t; i < nbkt; i += 256) cnt[i] = 0;
    for (int i = t; i < n; i += 256) {
        lsrc[i] = src[base + i];
        ldst[i] = dst[base + i];
    }
    __syncthreads();
    int rank[BINCHUNK / 256];
#pragma unroll
    for (int j = 0; j < BINCHUNK / 256; j++) {
        int i = t + j * 256;
        if (i < n) rank[j] = atomicAdd(&cnt[ldst[i] >> 7], 1);
    }
    __syncthreads();
    for (int b = t; b < nbkt; b += 256)
        if (cnt[b] > 0) gbase[b] = atomicAdd(&bcur[b], cnt[b]);
    __syncthreads();
#pragma unroll
    for (int j = 0; j < BINCHUNK / 256; j++) {
        int i = t + j * 256;
        if (i < n) {
            int d = ldst[i];
            unsigned w = (unsigned)lsrc[i] | ((unsigned)(d & (RB - 1)) << 20);
            pairB[gbase[d >> 7] + rank[j]] = w;
        }
    }
}

// ---- W1 -> fp16 transposed, padded [64][168], zero K-tail ------------------
__global__ void prep_w1_k(const float* __restrict__ W1, unsigned short* __restrict__ W1t) {
    int i = blockIdx.x * 256 + threadIdx.x;
    if (i >= 64 * 168) return;
    int n = i / 168, k = i % 168;
    float v = (k < 136) ? W1[k * 64 + n] : 0.0f;
    W1t[i] = f2h(v);
}

// ---- register-tiled GEMM: C[n,64] = act(A[n,K] @ W[K,64] (+b)) (x dinv) ----
template <int K, bool BIAS, bool RELU, bool F16OUT, bool DINV>
__global__ __launch_bounds__(256, 4) void lin_tile_k(
    const float* __restrict__ A, const float* __restrict__ W,
    const float* __restrict__ b, const float* __restrict__ dinv,
    void* __restrict__ outv, int n) {
    constexpr int KP = K + 4;
    __shared__ float As[128 * KP];
    __shared__ float Ws[64 * KP];
    int t = threadIdx.x;
    constexpr int K4 = K / 4;
    for (int i = t; i < 128 * K4; i += 256) {
        int r = i / K4, c4 = i % K4;
        int row = blockIdx.x * 128 + r;
        row = row < n ? row : n - 1;
        *(float4*)&As[r * KP + c4 * 4] = *(const float4*)&A[(size_t)row * K + c4 * 4];
    }
    for (int i = t; i < K * 64; i += 256) {
        int k = i >> 6, j = i & 63;
        Ws[j * KP + k] = W[i];
    }
    __syncthreads();
    int lane = t & 63;
    int wave = t >> 6;
    int ri = lane >> 3, ji = lane & 7;
    float acc[4][8];
#pragma unroll
    for (int m = 0; m < 4; m++)
#pragma unroll
        for (int c = 0; c < 8; c++) acc[m][c] = BIAS ? b[ji + 8 * c] : 0.0f;
#pragma unroll 2
    for (int kc = 0; kc < K; kc += 4) {
        float4 a[4], w[8];
#pragma unroll
        for (int m = 0; m < 4; m++)
            a[m] = *(const float4*)&As[(wave * 32 + ri + 8 * m) * KP + kc];
#pragma unroll
        for (int c = 0; c < 8; c++)
            w[c] = *(const float4*)&Ws[(ji + 8 * c) * KP + kc];
#pragma unroll
        for (int m = 0; m < 4; m++)
#pragma unroll
            for (int c = 0; c < 8; c++) {
                acc[m][c] = fmaf(a[m].x, w[c].x, acc[m][c]);
                acc[m][c] = fmaf(a[m].y, w[c].y, acc[m][c]);
                acc[m][c] = fmaf(a[m].z, w[c].z, acc[m][c]);
                acc[m][c] = fmaf(a[m].w, w[c].w, acc[m][c]);
            }
    }
#pragma unroll
    for (int m = 0; m < 4; m++) {
        int row = blockIdx.x * 128 + wave * 32 + ri + 8 * m;
        if (row < n) {
            float dv = DINV ? dinv[row] : 1.0f;
#pragma unroll
            for (int c = 0; c < 8; c++) {
                float v = acc[m][c];
                if (RELU) v = fmaxf(v, 0.0f);
                if (DINV) v *= dv;
                if (F16OUT) ((unsigned short*)outv)[(size_t)row * 64 + ji + 8 * c] = f2h(v);
                else        ((float*)outv)[(size_t)row * 64 + ji + 8 * c] = v;
            }
        }
    }
}

// ---- conv via bucket-local LDS accumulation --------------------------------
// Block b owns nodes [b*128,(b+1)*128): fp32 image in LDS (32KB). Waves stream
// the bucket's packed edges (coalesced), broadcast via shfl, one coalesced
// 128B row gather + 64 ds_add_f32 per edge (2-way bank alias = free).
// Hh pre-scaled by dinv[src]; epilogue: relu((img + Hh[d]) * dinv[d] + bias).
template <bool F16OUT>
__global__ __launch_bounds__(256) void conv_bucket_k(
    const unsigned short* __restrict__ Hh, const float* __restrict__ dinv,
    const int* __restrict__ rowptr, const unsigned int* __restrict__ pairB,
    const float* __restrict__ b, void* __restrict__ outv, int N) {
    __shared__ float img[RB * 64];  // 32 KB
    int t = threadIdx.x, lane = t & 63, wave = t >> 6;
    int node0 = blockIdx.x * RB;
    int nn = N - node0; if (nn > RB) nn = RB;
    for (int i = t; i < RB * 64 / 4; i += 256)
        ((float4*)img)[i] = (float4){0.f, 0.f, 0.f, 0.f};
    int beg = rowptr[node0];
    int end = rowptr[node0 + nn];
    float bv = b[lane];
    __syncthreads();
    for (int basei = beg + wave * 64; basei < end; basei += 256) {
        int m = end - basei; if (m > 64) m = 64;
        unsigned w = (lane < m) ? pairB[basei + lane] : 0u;
        int j = 0;
        for (; j + 8 <= m; j += 8) {
            float v[8]; int dl[8];
#pragma unroll
            for (int u = 0; u < 8; u++) {
                unsigned wj = __shfl(w, j + u);
                dl[u] = wj >> 20;
                v[u] = h2f(Hh[(size_t)(wj & 0xFFFFF) * 64 + lane]);
            }
#pragma unroll
            for (int u = 0; u < 8; u++)
                atomicAdd(&img[dl[u] * 64 + lane], v[u]);
        }
        for (; j < m; j++) {
            unsigned wj = __shfl(w, j);
            float v = h2f(Hh[(size_t)(wj & 0xFFFFF) * 64 + lane]);
            atomicAdd(&img[(wj >> 20) * 64 + lane], v);
        }
    }
    __syncthreads();
    for (int nl = wave; nl < nn; nl += 4) {
        int node = node0 + nl;
        float dv = dinv[node];
        float self = h2f(Hh[(size_t)node * 64 + lane]);  // already hW[d]*dinv[d]
        float v = fmaxf(fmaf(img[nl * 64 + lane] + self, dv, bv), 0.0f);
        if (F16OUT) ((unsigned short*)outv)[(size_t)node * 64 + lane] = f2h(v);
        else        ((float*)outv)[(size_t)node * 64 + lane] = v;
    }
}

// ---- edge MLP via MFMA, direct global->register gather, no LDS -------------
__global__ __launch_bounds__(256, 3) void edge_mlp_direct_k(
    const unsigned short* __restrict__ hb, const float* __restrict__ attr,
    const int* __restrict__ src, const int* __restrict__ dst,
    const unsigned short* __restrict__ W1t,  // [64][168] fp16, transposed+padded
    const float* __restrict__ b1, const float* __restrict__ W2,
    const float* __restrict__ b2, float* __restrict__ out, int E, int nwaves) {
    int t = threadIdx.x;
    int lane = t & 63;
    int col = lane & 15;
    int quad = lane >> 4;
    int wid = blockIdx.x * 4 + (t >> 6);

    half8 Wf[4][5];
#pragma unroll
    for (int nt = 0; nt < 4; nt++)
#pragma unroll
        for (int kc = 0; kc < 5; kc++)
            Wf[nt][kc] = *(const half8*)&W1t[(nt * 16 + col) * 168 + kc * 32 + quad * 8];
    float b1v[4], w2v[4];
#pragma unroll
    for (int nt = 0; nt < 4; nt++) {
        b1v[nt] = b1[nt * 16 + col];
        w2v[nt] = W2[nt * 16 + col];
    }
    float b2v = b2[0];

    for (int base = wid * 32; base < E; base += nwaves * 32) {
        f32x4 acc[2][4];
#pragma unroll
        for (int mt = 0; mt < 2; mt++)
#pragma unroll
            for (int nt = 0; nt < 4; nt++)
                acc[mt][nt] = (f32x4){b1v[nt], b1v[nt], b1v[nt], b1v[nt]};
#pragma unroll
        for (int mt = 0; mt < 2; mt++) {
            int e = base + mt * 16 + col;
            e = e < E ? e : E - 1;
            int s = src[e], d = dst[e];
            half8 a0 = *(const half8*)&hb[(size_t)s * 64 + quad * 8];
            half8 a1 = *(const half8*)&hb[(size_t)s * 64 + 32 + quad * 8];
            half8 a2 = *(const half8*)&hb[(size_t)d * 64 + quad * 8];
            half8 a3 = *(const half8*)&hb[(size_t)d * 64 + 32 + quad * 8];
            half8 a4;
            if (quad == 0) {
                float4 x0 = ((const float4*)attr)[(size_t)e * 2];
                float4 x1 = ((const float4*)attr)[(size_t)e * 2 + 1];
                a4[0] = (_Float16)x0.x; a4[1] = (_Float16)x0.y;
                a4[2] = (_Float16)x0.z; a4[3] = (_Float16)x0.w;
                a4[4] = (_Float16)x1.x; a4[5] = (_Float16)x1.y;
                a4[6] = (_Float16)x1.z; a4[7] = (_Float16)x1.w;
            } else {
                a4 = (half8)(_Float16)0.0f;
            }
#pragma unroll
            for (int nt = 0; nt < 4; nt++) {
                acc[mt][nt] = __builtin_amdgcn_mfma_f32_16x16x32_f16(a0, Wf[nt][0], acc[mt][nt], 0, 0, 0);
                acc[mt][nt] = __builtin_amdgcn_mfma_f32_16x16x32_f16(a1, Wf[nt][1], acc[mt][nt], 0, 0, 0);
                acc[mt][nt] = __builtin_amdgcn_mfma_f32_16x16x32_f16(a2, Wf[nt][2], acc[mt][nt], 0, 0, 0);
                acc[mt][nt] = __builtin_amdgcn_mfma_f32_16x16x32_f16(a3, Wf[nt][3], acc[mt][nt], 0, 0, 0);
                acc[mt][nt] = __builtin_amdgcn_mfma_f32_16x16x32_f16(a4, Wf[nt][4], acc[mt][nt], 0, 0, 0);
            }
        }
#pragma unroll
        for (int mt = 0; mt < 2; mt++)
#pragma unroll
            for (int reg = 0; reg < 4; reg++) {
                float p = 0.0f;
#pragma unroll
                for (int nt = 0; nt < 4; nt++)
                    p = fmaf(fmaxf(acc[mt][nt][reg], 0.0f), w2v[nt], p);
                p += __shfl_xor(p, 1);
                p += __shfl_xor(p, 2);
                p += __shfl_xor(p, 4);
                p += __shfl_xor(p, 8);
                if (col == 0) {
                    int e = base + mt * 16 + quad * 4 + reg;
                    if (e < E) out[e] = p + b2v;
                }
            }
    }
}

extern "C" void kernel_launch(void* const* d_in, const int* in_sizes, int n_in,
                              void* d_out, int out_size, void* d_ws, size_t ws_size,
                              hipStream_t stream) {
    const float* x    = (const float*)d_in[0];
    const float* attr = (const float*)d_in[1];
    const float* W_e  = (const float*)d_in[2];
    const float* b_e  = (const float*)d_in[3];
    const float* W_c1 = (const float*)d_in[4];
    const float* b_c1 = (const float*)d_in[5];
    const float* W_c2 = (const float*)d_in[6];
    const float* b_c2 = (const float*)d_in[7];
    const float* W_p1 = (const float*)d_in[8];
    const float* b_p1 = (const float*)d_in[9];
    const float* W_p2 = (const float*)d_in[10];
    const float* b_p2 = (const float*)d_in[11];
    const void*  ei   = d_in[12];
    int N = in_sizes[0] / 32;
    int E = in_sizes[1] / 8;
    int n1 = N + 1;
    int nbkt = (N + RB - 1) / RB;
    float* out = (float*)d_out;

    char* p = (char*)d_ws;
    auto alloc = [&](size_t bytes) { void* q = p; p += (bytes + 255) & ~(size_t)255; return q; };
    float* A            = (float*)alloc((size_t)N * 64 * 4);   // h0; hb aliases later
    float* B            = (float*)alloc((size_t)N * 64 * 4);   // h1
    unsigned short* Hh  = (unsigned short*)alloc((size_t)N * 64 * 2);  // fp16 hW*dinv
    float* dinv         = (float*)alloc((size_t)N * 4);
    int* srcI           = (int*)alloc((size_t)E * 4);
    int* dstI           = (int*)alloc((size_t)E * 4);
    unsigned int* pairB = (unsigned int*)alloc((size_t)E * 4);
    int* deg            = (int*)alloc((size_t)n1 * 4);
    int* rowptr         = (int*)alloc((size_t)n1 * 4);
    int* part           = (int*)alloc((size_t)n1 * 4);
    int* bsum           = (int*)alloc(512 * 4);
    int* bcur           = (int*)alloc((size_t)nbkt * 4);
    unsigned short* W1t = (unsigned short*)alloc(64 * 168 * 2);
    int* flag           = (int*)alloc(4);
    unsigned short* hb = (unsigned short*)A;  // h0 dead after lin of conv2

    auto cdiv = [](long long a, long long b) { return (int)((a + b - 1) / b); };

    detect_idx_k<<<1, 64, 0, stream>>>((const unsigned int*)ei, flag);
    hipMemsetAsync(deg, 0, (size_t)n1 * 4, stream);
    cvt_deg_k<<<cdiv(2LL * E, 256), 256, 0, stream>>>(ei, flag, srcI, deg, E);
    int nb = cdiv(n1, 256);
    scan_blk_k<<<nb, 256, 0, stream>>>(deg, part, bsum, n1);
    scan_tot_k<<<1, 512, 0, stream>>>(bsum, nb);
    scan_add_k<<<nb, 256, 0, stream>>>(part, bsum, rowptr, n1);
    dinv_k<<<cdiv(N, 256), 256, 0, stream>>>(deg, dinv, N);
    bcur_init_k<<<cdiv(nbkt, 256), 256, 0, stream>>>(rowptr, bcur, nbkt);
    bin_k<<<cdiv(E, BINCHUNK), 256, 0, stream>>>(srcI, dstI, bcur, pairB, E, nbkt);
    prep_w1_k<<<cdiv(64 * 168, 256), 256, 0, stream>>>(W_p1, W1t);
    // network
    int lg = cdiv(N, 128);
    lin_tile_k<32, true, true, false, false><<<lg, 256, 0, stream>>>(x, W_e, b_e, nullptr, A, N);
    lin_tile_k<64, false, false, true, true><<<lg, 256, 0, stream>>>(A, W_c1, nullptr, dinv, Hh, N);
    conv_bucket_k<false><<<nbkt, 256, 0, stream>>>(Hh, dinv, rowptr, pairB, b_c1, B, N);
    lin_tile_k<64, false, false, true, true><<<lg, 256, 0, stream>>>(B, W_c2, nullptr, dinv, Hh, N);
    conv_bucket_k<true><<<nbkt, 256, 0, stream>>>(Hh, dinv, rowptr, pairB, b_c2, hb, N);
    const int NB = 768;
    edge_mlp_direct_k<<<NB, 256, 0, stream>>>(hb, attr, srcI, dstI, W1t,
                                              b_p1, W_p2, b_p2, out, E, NB * 4);
}

// Round 7
// 1791.150 us; speedup vs baseline: 1.0007x; 1.0007x over previous
//
#include <hip/hip_runtime.h>
#include <hip/hip_fp16.h>

// ---------------------------------------------------------------------------
// GNN traffic predictor: embed -> GCNConv x2 -> edge MLP
// N=100000, E=1600000, F_NODE=32, F_EDGE=8, H=64
// Round 7: fix round-6's conv_bucket_k LDS atomic -- plain atomicAdd(shared
// float) compiled to a CAS retry loop (716us, VALUBusy 3%, all pipes idle);
// unsafeAtomicAdd lowers to fire-and-forget ds_add_f32. No other changes.
// ---------------------------------------------------------------------------

typedef __attribute__((ext_vector_type(8))) _Float16 half8;
typedef __attribute__((ext_vector_type(4))) float f32x4;

__device__ __forceinline__ unsigned short f2h(float f) {
    return __half_as_ushort(__float2half(f));
}
__device__ __forceinline__ float h2f(unsigned short u) {
    return __half2float(__ushort_as_half(u));
}

#define RB 128           // nodes per bucket
#define NBKT 782         // ceil(100000/128); recomputed at launch
#define BINCHUNK 4096    // edges per bin_k block

// ---- index dtype detection: flag=1 -> int32, 0 -> int64 --------------------
__global__ void detect_idx_k(const unsigned int* __restrict__ ei, int* __restrict__ flag) {
    int nz = 0;
    for (int i = threadIdx.x; i < 2048; i += 64)
        if (ei[2 * i + 1] != 0u) nz = 1;
    unsigned long long m = __ballot(nz);
    if (threadIdx.x == 0) *flag = (m != 0ull) ? 1 : 0;
}

// ---- fused index convert + degree count ------------------------------------
__global__ void cvt_deg_k(const void* __restrict__ ei, const int* __restrict__ flag,
                          int* __restrict__ out, int* __restrict__ deg, int E) {
    int i = blockIdx.x * 256 + threadIdx.x;
    if (i >= 2 * E) return;
    int v;
    if (*flag) v = ((const int*)ei)[i];
    else       v = (int)((const long long*)ei)[i];
    out[i] = v;
    if (i >= E) atomicAdd(&deg[v], 1);  // dst half
}

// ---- rowptr scan -----------------------------------------------------------
__global__ void scan_blk_k(const int* __restrict__ deg, int* __restrict__ part,
                           int* __restrict__ bsum, int n1) {
    __shared__ int s[256];
    int t = threadIdx.x;
    int i = blockIdx.x * 256 + t;
    int v = (i < n1) ? deg[i] : 0;
    s[t] = v;
    __syncthreads();
    for (int o = 1; o < 256; o <<= 1) {
        int x = (t >= o) ? s[t - o] : 0;
        __syncthreads();
        s[t] += x;
        __syncthreads();
    }
    if (i < n1) part[i] = s[t] - v;  // exclusive
    if (t == 255) bsum[blockIdx.x] = s[255];
}

__global__ void scan_tot_k(int* __restrict__ bsum, int nb) {
    __shared__ int s[512];
    int t = threadIdx.x;
    int v = (t < nb) ? bsum[t] : 0;
    s[t] = v;
    __syncthreads();
    for (int o = 1; o < 512; o <<= 1) {
        int x = (t >= o) ? s[t - o] : 0;
        __syncthreads();
        s[t] += x;
        __syncthreads();
    }
    if (t < nb) bsum[t] = s[t] - v;
}

__global__ void scan_add_k(const int* __restrict__ part, const int* __restrict__ bsum,
                           int* __restrict__ rowptr, int n1) {
    int i = blockIdx.x * 256 + threadIdx.x;
    if (i < n1) rowptr[i] = part[i] + bsum[blockIdx.x];
}

__global__ void dinv_k(const int* __restrict__ deg, float* __restrict__ dinv, int n) {
    int i = blockIdx.x * 256 + threadIdx.x;
    if (i < n) dinv[i] = rsqrtf((float)deg[i] + 1.0f);  // +1 self-loop
}

__global__ void bcur_init_k(const int* __restrict__ rowptr, int* __restrict__ bcur,
                            int nbkt) {
    int b = blockIdx.x * 256 + threadIdx.x;
    if (b < nbkt) bcur[b] = rowptr[b * RB];
}

// ---- bucket binning: pairB[slot] = src | (dst&127)<<20, grouped by dst>>7 --
__global__ __launch_bounds__(256) void bin_k(
    const int* __restrict__ src, const int* __restrict__ dst,
    int* __restrict__ bcur, unsigned int* __restrict__ pairB, int E, int nbkt) {
    __shared__ int lsrc[BINCHUNK];
    __shared__ int ldst[BINCHUNK];
    __shared__ int cnt[NBKT], gbase[NBKT];
    int t = threadIdx.x;
    int base = blockIdx.x * BINCHUNK;
    int n = E - base; if (n > BINCHUNK) n = BINCHUNK;
    for (int i = t; i < nbkt; i += 256) cnt[i] = 0;
    for (int i = t; i < n; i += 256) {
        lsrc[i] = src[base + i];
        ldst[i] = dst[base + i];
    }
    __syncthreads();
    int rank[BINCHUNK / 256];
#pragma unroll
    for (int j = 0; j < BINCHUNK / 256; j++) {
        int i = t + j * 256;
        if (i < n) rank[j] = atomicAdd(&cnt[ldst[i] >> 7], 1);
    }
    __syncthreads();
    for (int b = t; b < nbkt; b += 256)
        if (cnt[b] > 0) gbase[b] = atomicAdd(&bcur[b], cnt[b]);
    __syncthreads();
#pragma unroll
    for (int j = 0; j < BINCHUNK / 256; j++) {
        int i = t + j * 256;
        if (i < n) {
            int d = ldst[i];
            unsigned w = (unsigned)lsrc[i] | ((unsigned)(d & (RB - 1)) << 20);
            pairB[gbase[d >> 7] + rank[j]] = w;
        }
    }
}

// ---- W1 -> fp16 transposed, padded [64][168], zero K-tail ------------------
__global__ void prep_w1_k(const float* __restrict__ W1, unsigned short* __restrict__ W1t) {
    int i = blockIdx.x * 256 + threadIdx.x;
    if (i >= 64 * 168) return;
    int n = i / 168, k = i % 168;
    float v = (k < 136) ? W1[k * 64 + n] : 0.0f;
    W1t[i] = f2h(v);
}

// ---- register-tiled GEMM: C[n,64] = act(A[n,K] @ W[K,64] (+b)) (x dinv) ----
template <int K, bool BIAS, bool RELU, bool F16OUT, bool DINV>
__global__ __launch_bounds__(256, 4) void lin_tile_k(
    const float* __restrict__ A, const float* __restrict__ W,
    const float* __restrict__ b, const float* __restrict__ dinv,
    void* __restrict__ outv, int n) {
    constexpr int KP = K + 4;
    __shared__ float As[128 * KP];
    __shared__ float Ws[64 * KP];
    int t = threadIdx.x;
    constexpr int K4 = K / 4;
    for (int i = t; i < 128 * K4; i += 256) {
        int r = i / K4, c4 = i % K4;
        int row = blockIdx.x * 128 + r;
        row = row < n ? row : n - 1;
        *(float4*)&As[r * KP + c4 * 4] = *(const float4*)&A[(size_t)row * K + c4 * 4];
    }
    for (int i = t; i < K * 64; i += 256) {
        int k = i >> 6, j = i & 63;
        Ws[j * KP + k] = W[i];
    }
    __syncthreads();
    int lane = t & 63;
    int wave = t >> 6;
    int ri = lane >> 3, ji = lane & 7;
    float acc[4][8];
#pragma unroll
    for (int m = 0; m < 4; m++)
#pragma unroll
        for (int c = 0; c < 8; c++) acc[m][c] = BIAS ? b[ji + 8 * c] : 0.0f;
#pragma unroll 2
    for (int kc = 0; kc < K; kc += 4) {
        float4 a[4], w[8];
#pragma unroll
        for (int m = 0; m < 4; m++)
            a[m] = *(const float4*)&As[(wave * 32 + ri + 8 * m) * KP + kc];
#pragma unroll
        for (int c = 0; c < 8; c++)
            w[c] = *(const float4*)&Ws[(ji + 8 * c) * KP + kc];
#pragma unroll
        for (int m = 0; m < 4; m++)
#pragma unroll
            for (int c = 0; c < 8; c++) {
                acc[m][c] = fmaf(a[m].x, w[c].x, acc[m][c]);
                acc[m][c] = fmaf(a[m].y, w[c].y, acc[m][c]);
                acc[m][c] = fmaf(a[m].z, w[c].z, acc[m][c]);
                acc[m][c] = fmaf(a[m].w, w[c].w, acc[m][c]);
            }
    }
#pragma unroll
    for (int m = 0; m < 4; m++) {
        int row = blockIdx.x * 128 + wave * 32 + ri + 8 * m;
        if (row < n) {
            float dv = DINV ? dinv[row] : 1.0f;
#pragma unroll
            for (int c = 0; c < 8; c++) {
                float v = acc[m][c];
                if (RELU) v = fmaxf(v, 0.0f);
                if (DINV) v *= dv;
                if (F16OUT) ((unsigned short*)outv)[(size_t)row * 64 + ji + 8 * c] = f2h(v);
                else        ((float*)outv)[(size_t)row * 64 + ji + 8 * c] = v;
            }
        }
    }
}

// ---- conv via bucket-local LDS accumulation --------------------------------
// unsafeAtomicAdd -> ds_add_f32 (fire-and-forget). Round-6's atomicAdd
// compiled to a CAS retry loop: 716us with every pipe <3% busy.
template <bool F16OUT>
__global__ __launch_bounds__(256) void conv_bucket_k(
    const unsigned short* __restrict__ Hh, const float* __restrict__ dinv,
    const int* __restrict__ rowptr, const unsigned int* __restrict__ pairB,
    const float* __restrict__ b, void* __restrict__ outv, int N) {
    __shared__ float img[RB * 64];  // 32 KB
    int t = threadIdx.x, lane = t & 63, wave = t >> 6;
    int node0 = blockIdx.x * RB;
    int nn = N - node0; if (nn > RB) nn = RB;
    for (int i = t; i < RB * 64 / 4; i += 256)
        ((float4*)img)[i] = (float4){0.f, 0.f, 0.f, 0.f};
    int beg = rowptr[node0];
    int end = rowptr[node0 + nn];
    float bv = b[lane];
    __syncthreads();
    for (int basei = beg + wave * 64; basei < end; basei += 256) {
        int m = end - basei; if (m > 64) m = 64;
        unsigned w = (lane < m) ? pairB[basei + lane] : 0u;
        int j = 0;
        for (; j + 8 <= m; j += 8) {
            float v[8]; int dl[8];
#pragma unroll
            for (int u = 0; u < 8; u++) {
                unsigned wj = __shfl(w, j + u);
                dl[u] = wj >> 20;
                v[u] = h2f(Hh[(size_t)(wj & 0xFFFFF) * 64 + lane]);
            }
#pragma unroll
            for (int u = 0; u < 8; u++)
                unsafeAtomicAdd(&img[dl[u] * 64 + lane], v[u]);
        }
        for (; j < m; j++) {
            unsigned wj = __shfl(w, j);
            float v = h2f(Hh[(size_t)(wj & 0xFFFFF) * 64 + lane]);
            unsafeAtomicAdd(&img[(wj >> 20) * 64 + lane], v);
        }
    }
    __syncthreads();
    for (int nl = wave; nl < nn; nl += 4) {
        int node = node0 + nl;
        float dv = dinv[node];
        float self = h2f(Hh[(size_t)node * 64 + lane]);  // already hW[d]*dinv[d]
        float v = fmaxf(fmaf(img[nl * 64 + lane] + self, dv, bv), 0.0f);
        if (F16OUT) ((unsigned short*)outv)[(size_t)node * 64 + lane] = f2h(v);
        else        ((float*)outv)[(size_t)node * 64 + lane] = v;
    }
}

// ---- edge MLP via MFMA, direct global->register gather, no LDS -------------
__global__ __launch_bounds__(256, 3) void edge_mlp_direct_k(
    const unsigned short* __restrict__ hb, const float* __restrict__ attr,
    const int* __restrict__ src, const int* __restrict__ dst,
    const unsigned short* __restrict__ W1t,  // [64][168] fp16, transposed+padded
    const float* __restrict__ b1, const float* __restrict__ W2,
    const float* __restrict__ b2, float* __restrict__ out, int E, int nwaves) {
    int t = threadIdx.x;
    int lane = t & 63;
    int col = lane & 15;
    int quad = lane >> 4;
    int wid = blockIdx.x * 4 + (t >> 6);

    half8 Wf[4][5];
#pragma unroll
    for (int nt = 0; nt < 4; nt++)
#pragma unroll
        for (int kc = 0; kc < 5; kc++)
            Wf[nt][kc] = *(const half8*)&W1t[(nt * 16 + col) * 168 + kc * 32 + quad * 8];
    float b1v[4], w2v[4];
#pragma unroll
    for (int nt = 0; nt < 4; nt++) {
        b1v[nt] = b1[nt * 16 + col];
        w2v[nt] = W2[nt * 16 + col];
    }
    float b2v = b2[0];

    for (int base = wid * 32; base < E; base += nwaves * 32) {
        f32x4 acc[2][4];
#pragma unroll
        for (int mt = 0; mt < 2; mt++)
#pragma unroll
            for (int nt = 0; nt < 4; nt++)
                acc[mt][nt] = (f32x4){b1v[nt], b1v[nt], b1v[nt], b1v[nt]};
#pragma unroll
        for (int mt = 0; mt < 2; mt++) {
            int e = base + mt * 16 + col;
            e = e < E ? e : E - 1;
            int s = src[e], d = dst[e];
            half8 a0 = *(const half8*)&hb[(size_t)s * 64 + quad * 8];
            half8 a1 = *(const half8*)&hb[(size_t)s * 64 + 32 + quad * 8];
            half8 a2 = *(const half8*)&hb[(size_t)d * 64 + quad * 8];
            half8 a3 = *(const half8*)&hb[(size_t)d * 64 + 32 + quad * 8];
            half8 a4;
            if (quad == 0) {
                float4 x0 = ((const float4*)attr)[(size_t)e * 2];
                float4 x1 = ((const float4*)attr)[(size_t)e * 2 + 1];
                a4[0] = (_Float16)x0.x; a4[1] = (_Float16)x0.y;
                a4[2] = (_Float16)x0.z; a4[3] = (_Float16)x0.w;
                a4[4] = (_Float16)x1.x; a4[5] = (_Float16)x1.y;
                a4[6] = (_Float16)x1.z; a4[7] = (_Float16)x1.w;
            } else {
                a4 = (half8)(_Float16)0.0f;
            }
#pragma unroll
            for (int nt = 0; nt < 4; nt++) {
                acc[mt][nt] = __builtin_amdgcn_mfma_f32_16x16x32_f16(a0, Wf[nt][0], acc[mt][nt], 0, 0, 0);
                acc[mt][nt] = __builtin_amdgcn_mfma_f32_16x16x32_f16(a1, Wf[nt][1], acc[mt][nt], 0, 0, 0);
                acc[mt][nt] = __builtin_amdgcn_mfma_f32_16x16x32_f16(a2, Wf[nt][2], acc[mt][nt], 0, 0, 0);
                acc[mt][nt] = __builtin_amdgcn_mfma_f32_16x16x32_f16(a3, Wf[nt][3], acc[mt][nt], 0, 0, 0);
                acc[mt][nt] = __builtin_amdgcn_mfma_f32_16x16x32_f16(a4, Wf[nt][4], acc[mt][nt], 0, 0, 0);
            }
        }
#pragma unroll
        for (int mt = 0; mt < 2; mt++)
#pragma unroll
            for (int reg = 0; reg < 4; reg++) {
                float p = 0.0f;
#pragma unroll
                for (int nt = 0; nt < 4; nt++)
                    p = fmaf(fmaxf(acc[mt][nt][reg], 0.0f), w2v[nt], p);
                p += __shfl_xor(p, 1);
                p += __shfl_xor(p, 2);
                p += __shfl_xor(p, 4);
                p += __shfl_xor(p, 8);
                if (col == 0) {
                    int e = base + mt * 16 + quad * 4 + reg;
                    if (e < E) out[e] = p + b2v;
                }
            }
    }
}

extern "C" void kernel_launch(void* const* d_in, const int* in_sizes, int n_in,
                              void* d_out, int out_size, void* d_ws, size_t ws_size,
                              hipStream_t stream) {
    const float* x    = (const float*)d_in[0];
    const float* attr = (const float*)d_in[1];
    const float* W_e  = (const float*)d_in[2];
    const float* b_e  = (const float*)d_in[3];
    const float* W_c1 = (const float*)d_in[4];
    const float* b_c1 = (const float*)d_in[5];
    const float* W_c2 = (const float*)d_in[6];
    const float* b_c2 = (const float*)d_in[7];
    const float* W_p1 = (const float*)d_in[8];
    const float* b_p1 = (const float*)d_in[9];
    const float* W_p2 = (const float*)d_in[10];
    const float* b_p2 = (const float*)d_in[11];
    const void*  ei   = d_in[12];
    int N = in_sizes[0] / 32;
    int E = in_sizes[1] / 8;
    int n1 = N + 1;
    int nbkt = (N + RB - 1) / RB;
    float* out = (float*)d_out;

    char* p = (char*)d_ws;
    auto alloc = [&](size_t bytes) { void* q = p; p += (bytes + 255) & ~(size_t)255; return q; };
    float* A            = (float*)alloc((size_t)N * 64 * 4);   // h0; hb aliases later
    float* B            = (float*)alloc((size_t)N * 64 * 4);   // h1
    unsigned short* Hh  = (unsigned short*)alloc((size_t)N * 64 * 2);  // fp16 hW*dinv
    float* dinv         = (float*)alloc((size_t)N * 4);
    int* srcI           = (int*)alloc((size_t)E * 4);
    int* dstI           = (int*)alloc((size_t)E * 4);
    unsigned int* pairB = (unsigned int*)alloc((size_t)E * 4);
    int* deg            = (int*)alloc((size_t)n1 * 4);
    int* rowptr         = (int*)alloc((size_t)n1 * 4);
    int* part           = (int*)alloc((size_t)n1 * 4);
    int* bsum           = (int*)alloc(512 * 4);
    int* bcur           = (int*)alloc((size_t)nbkt * 4);
    unsigned short* W1t = (unsigned short*)alloc(64 * 168 * 2);
    int* flag           = (int*)alloc(4);
    unsigned short* hb = (unsigned short*)A;  // h0 dead after lin of conv2

    auto cdiv = [](long long a, long long b) { return (int)((a + b - 1) / b); };

    detect_idx_k<<<1, 64, 0, stream>>>((const unsigned int*)ei, flag);
    hipMemsetAsync(deg, 0, (size_t)n1 * 4, stream);
    cvt_deg_k<<<cdiv(2LL * E, 256), 256, 0, stream>>>(ei, flag, srcI, deg, E);
    int nb = cdiv(n1, 256);
    scan_blk_k<<<nb, 256, 0, stream>>>(deg, part, bsum, n1);
    scan_tot_k<<<1, 512, 0, stream>>>(bsum, nb);
    scan_add_k<<<nb, 256, 0, stream>>>(part, bsum, rowptr, n1);
    dinv_k<<<cdiv(N, 256), 256, 0, stream>>>(deg, dinv, N);
    bcur_init_k<<<cdiv(nbkt, 256), 256, 0, stream>>>(rowptr, bcur, nbkt);
    bin_k<<<cdiv(E, BINCHUNK), 256, 0, stream>>>(srcI, dstI, bcur, pairB, E, nbkt);
    prep_w1_k<<<cdiv(64 * 168, 256), 256, 0, stream>>>(W_p1, W1t);
    // network
    int lg = cdiv(N, 128);
    lin_tile_k<32, true, true, false, false><<<lg, 256, 0, stream>>>(x, W_e, b_e, nullptr, A, N);
    lin_tile_k<64, false, false, true, true><<<lg, 256, 0, stream>>>(A, W_c1, nullptr, dinv, Hh, N);
    conv_bucket_k<false><<<nbkt, 256, 0, stream>>>(Hh, dinv, rowptr, pairB, b_c1, B, N);
    lin_tile_k<64, false, false, true, true><<<lg, 256, 0, stream>>>(B, W_c2, nullptr, dinv, Hh, N);
    conv_bucket_k<true><<<nbkt, 256, 0, stream>>>(Hh, dinv, rowptr, pairB, b_c2, hb, N);
    const int NB = 768;
    edge_mlp_direct_k<<<NB, 256, 0, stream>>>(hb, attr, srcI, dstI, W1t,
                                              b_p1, W_p2, b_p2, out, E, NB * 4);
}

// Round 8
// 669.323 us; speedup vs baseline: 2.6781x; 2.6761x over previous
//
#include <hip/hip_runtime.h>
#include <hip/hip_fp16.h>

// ---------------------------------------------------------------------------
// GNN traffic predictor: embed -> GCNConv x2 -> edge MLP
// N=100000, E=1600000, F_NODE=32, F_EDGE=8, H=64
// Round 8: conv rewritten as bucket-local LDS counting sort + register
// accumulation. Rounds 6/7 (per-edge __shfl broadcast + LDS float atomic)
// were chain-latency bound at 715us with all pipes <3.5% busy: lgkmcnt
// drains in-order, so each group's bpermute wait also drained the atomics --
// no pipelining. New inner loop = uniform ds_read + coalesced row load +
// register fmaf (the measured-good round-5 conv_gather pattern), no atomics.
// ---------------------------------------------------------------------------

typedef __attribute__((ext_vector_type(8))) _Float16 half8;
typedef __attribute__((ext_vector_type(4))) float f32x4;

__device__ __forceinline__ unsigned short f2h(float f) {
    return __half_as_ushort(__float2half(f));
}
__device__ __forceinline__ float h2f(unsigned short u) {
    return __half2float(__ushort_as_half(u));
}

#define RB 128           // nodes per bucket
#define NBKT 782         // ceil(100000/128); recomputed at launch
#define BINCHUNK 4096    // edges per bin_k block
#define CCH 2048         // conv sort chunk (edges)

// ---- index dtype detection: flag=1 -> int32, 0 -> int64 --------------------
__global__ void detect_idx_k(const unsigned int* __restrict__ ei, int* __restrict__ flag) {
    int nz = 0;
    for (int i = threadIdx.x; i < 2048; i += 64)
        if (ei[2 * i + 1] != 0u) nz = 1;
    unsigned long long m = __ballot(nz);
    if (threadIdx.x == 0) *flag = (m != 0ull) ? 1 : 0;
}

// ---- fused index convert + degree count ------------------------------------
__global__ void cvt_deg_k(const void* __restrict__ ei, const int* __restrict__ flag,
                          int* __restrict__ out, int* __restrict__ deg, int E) {
    int i = blockIdx.x * 256 + threadIdx.x;
    if (i >= 2 * E) return;
    int v;
    if (*flag) v = ((const int*)ei)[i];
    else       v = (int)((const long long*)ei)[i];
    out[i] = v;
    if (i >= E) atomicAdd(&deg[v], 1);  // dst half
}

// ---- rowptr scan -----------------------------------------------------------
__global__ void scan_blk_k(const int* __restrict__ deg, int* __restrict__ part,
                           int* __restrict__ bsum, int n1) {
    __shared__ int s[256];
    int t = threadIdx.x;
    int i = blockIdx.x * 256 + t;
    int v = (i < n1) ? deg[i] : 0;
    s[t] = v;
    __syncthreads();
    for (int o = 1; o < 256; o <<= 1) {
        int x = (t >= o) ? s[t - o] : 0;
        __syncthreads();
        s[t] += x;
        __syncthreads();
    }
    if (i < n1) part[i] = s[t] - v;  // exclusive
    if (t == 255) bsum[blockIdx.x] = s[255];
}

__global__ void scan_tot_k(int* __restrict__ bsum, int nb) {
    __shared__ int s[512];
    int t = threadIdx.x;
    int v = (t < nb) ? bsum[t] : 0;
    s[t] = v;
    __syncthreads();
    for (int o = 1; o < 512; o <<= 1) {
        int x = (t >= o) ? s[t - o] : 0;
        __syncthreads();
        s[t] += x;
        __syncthreads();
    }
    if (t < nb) bsum[t] = s[t] - v;
}

__global__ void scan_add_k(const int* __restrict__ part, const int* __restrict__ bsum,
                           int* __restrict__ rowptr, int n1) {
    int i = blockIdx.x * 256 + threadIdx.x;
    if (i < n1) rowptr[i] = part[i] + bsum[blockIdx.x];
}

__global__ void dinv_k(const int* __restrict__ deg, float* __restrict__ dinv, int n) {
    int i = blockIdx.x * 256 + threadIdx.x;
    if (i < n) dinv[i] = rsqrtf((float)deg[i] + 1.0f);  // +1 self-loop
}

__global__ void bcur_init_k(const int* __restrict__ rowptr, int* __restrict__ bcur,
                            int nbkt) {
    int b = blockIdx.x * 256 + threadIdx.x;
    if (b < nbkt) bcur[b] = rowptr[b * RB];
}

// ---- bucket binning: pairB[slot] = src | (dst&127)<<20, grouped by dst>>7 --
__global__ __launch_bounds__(256) void bin_k(
    const int* __restrict__ src, const int* __restrict__ dst,
    int* __restrict__ bcur, unsigned int* __restrict__ pairB, int E, int nbkt) {
    __shared__ int lsrc[BINCHUNK];
    __shared__ int ldst[BINCHUNK];
    __shared__ int cnt[NBKT], gbase[NBKT];
    int t = threadIdx.x;
    int base = blockIdx.x * BINCHUNK;
    int n = E - base; if (n > BINCHUNK) n = BINCHUNK;
    for (int i = t; i < nbkt; i += 256) cnt[i] = 0;
    for (int i = t; i < n; i += 256) {
        lsrc[i] = src[base + i];
        ldst[i] = dst[base + i];
    }
    __syncthreads();
    int rank[BINCHUNK / 256];
#pragma unroll
    for (int j = 0; j < BINCHUNK / 256; j++) {
        int i = t + j * 256;
        if (i < n) rank[j] = atomicAdd(&cnt[ldst[i] >> 7], 1);
    }
    __syncthreads();
    for (int b = t; b < nbkt; b += 256)
        if (cnt[b] > 0) gbase[b] = atomicAdd(&bcur[b], cnt[b]);
    __syncthreads();
#pragma unroll
    for (int j = 0; j < BINCHUNK / 256; j++) {
        int i = t + j * 256;
        if (i < n) {
            int d = ldst[i];
            unsigned w = (unsigned)lsrc[i] | ((unsigned)(d & (RB - 1)) << 20);
            pairB[gbase[d >> 7] + rank[j]] = w;
        }
    }
}

// ---- W1 -> fp16 transposed, padded [64][168], zero K-tail ------------------
__global__ void prep_w1_k(const float* __restrict__ W1, unsigned short* __restrict__ W1t) {
    int i = blockIdx.x * 256 + threadIdx.x;
    if (i >= 64 * 168) return;
    int n = i / 168, k = i % 168;
    float v = (k < 136) ? W1[k * 64 + n] : 0.0f;
    W1t[i] = f2h(v);
}

// ---- register-tiled GEMM: C[n,64] = act(A[n,K] @ W[K,64] (+b)) (x dinv) ----
template <int K, bool BIAS, bool RELU, bool F16OUT, bool DINV>
__global__ __launch_bounds__(256, 4) void lin_tile_k(
    const float* __restrict__ A, const float* __restrict__ W,
    const float* __restrict__ b, const float* __restrict__ dinv,
    void* __restrict__ outv, int n) {
    constexpr int KP = K + 4;
    __shared__ float As[128 * KP];
    __shared__ float Ws[64 * KP];
    int t = threadIdx.x;
    constexpr int K4 = K / 4;
    for (int i = t; i < 128 * K4; i += 256) {
        int r = i / K4, c4 = i % K4;
        int row = blockIdx.x * 128 + r;
        row = row < n ? row : n - 1;
        *(float4*)&As[r * KP + c4 * 4] = *(const float4*)&A[(size_t)row * K + c4 * 4];
    }
    for (int i = t; i < K * 64; i += 256) {
        int k = i >> 6, j = i & 63;
        Ws[j * KP + k] = W[i];
    }
    __syncthreads();
    int lane = t & 63;
    int wave = t >> 6;
    int ri = lane >> 3, ji = lane & 7;
    float acc[4][8];
#pragma unroll
    for (int m = 0; m < 4; m++)
#pragma unroll
        for (int c = 0; c < 8; c++) acc[m][c] = BIAS ? b[ji + 8 * c] : 0.0f;
#pragma unroll 2
    for (int kc = 0; kc < K; kc += 4) {
        float4 a[4], w[8];
#pragma unroll
        for (int m = 0; m < 4; m++)
            a[m] = *(const float4*)&As[(wave * 32 + ri + 8 * m) * KP + kc];
#pragma unroll
        for (int c = 0; c < 8; c++)
            w[c] = *(const float4*)&Ws[(ji + 8 * c) * KP + kc];
#pragma unroll
        for (int m = 0; m < 4; m++)
#pragma unroll
            for (int c = 0; c < 8; c++) {
                acc[m][c] = fmaf(a[m].x, w[c].x, acc[m][c]);
                acc[m][c] = fmaf(a[m].y, w[c].y, acc[m][c]);
                acc[m][c] = fmaf(a[m].z, w[c].z, acc[m][c]);
                acc[m][c] = fmaf(a[m].w, w[c].w, acc[m][c]);
            }
    }
#pragma unroll
    for (int m = 0; m < 4; m++) {
        int row = blockIdx.x * 128 + wave * 32 + ri + 8 * m;
        if (row < n) {
            float dv = DINV ? dinv[row] : 1.0f;
#pragma unroll
            for (int c = 0; c < 8; c++) {
                float v = acc[m][c];
                if (RELU) v = fmaxf(v, 0.0f);
                if (DINV) v *= dv;
                if (F16OUT) ((unsigned short*)outv)[(size_t)row * 64 + ji + 8 * c] = f2h(v);
                else        ((float*)outv)[(size_t)row * 64 + ji + 8 * c] = v;
            }
        }
    }
}

// ---- conv: bucket-local counting sort + register accumulation --------------
// Block = 128-node bucket. Per 2048-edge chunk: count (int LDS atomics, native
// ds_add), scan, sort srcs into per-node contiguous LDS lists; then each wave
// register-accumulates its 32 nodes with uniform ds_read + coalesced Hh row
// loads -- no atomics, no shfl in the hot loop.
template <bool F16OUT>
__global__ __launch_bounds__(256) void conv_sorted_k(
    const unsigned short* __restrict__ Hh, const float* __restrict__ dinv,
    const int* __restrict__ rowptr, const unsigned int* __restrict__ pairB,
    const float* __restrict__ b, void* __restrict__ outv, int N) {
    __shared__ unsigned int ew[CCH];
    __shared__ int srt[CCH];
    __shared__ int cnt[RB];
    __shared__ int sc[RB];
    __shared__ int cur[RB];
    int t = threadIdx.x, lane = t & 63, wave = t >> 6;
    int node0 = blockIdx.x * RB;
    int nn = N - node0; if (nn > RB) nn = RB;
    int beg = rowptr[node0], end = rowptr[node0 + nn];
    float acc[32];
#pragma unroll
    for (int q = 0; q < 32; q++) acc[q] = 0.0f;

    for (int cbeg = beg; cbeg < end; cbeg += CCH) {
        int cn = end - cbeg; if (cn > CCH) cn = CCH;
        if (t < RB) cnt[t] = 0;
        __syncthreads();
        for (int i = t; i < cn; i += 256) {
            unsigned w = pairB[cbeg + i];
            ew[i] = w;
            atomicAdd(&cnt[w >> 20], 1);  // int LDS atomic: native ds_add
        }
        __syncthreads();
        if (t < RB) sc[t] = cnt[t];
        __syncthreads();
        for (int o = 1; o < RB; o <<= 1) {
            int v = 0;
            if (t < RB && t >= o) v = sc[t - o];
            __syncthreads();
            if (t < RB) sc[t] += v;
            __syncthreads();
        }
        if (t < RB) cur[t] = sc[t] - cnt[t];
        __syncthreads();
        for (int i = t; i < cn; i += 256) {
            unsigned w = ew[i];
            int d = (int)(w >> 20);
            int r = atomicAdd(&cur[d], 1);
            srt[r] = (int)(w & 0xFFFFF);
        }
        __syncthreads();
        // gather: wave handles nodes [wave*32, wave*32+32)
#pragma unroll
        for (int q = 0; q < 32; q++) {
            int nl = wave * 32 + q;
            int e1 = sc[nl];
            int i = e1 - cnt[nl];
            float a = acc[q];
            for (; i + 8 <= e1; i += 8) {
                int s0 = srt[i], s1 = srt[i + 1], s2 = srt[i + 2], s3 = srt[i + 3];
                int s4 = srt[i + 4], s5 = srt[i + 5], s6 = srt[i + 6], s7 = srt[i + 7];
                float v0 = h2f(Hh[(size_t)s0 * 64 + lane]);
                float v1 = h2f(Hh[(size_t)s1 * 64 + lane]);
                float v2 = h2f(Hh[(size_t)s2 * 64 + lane]);
                float v3 = h2f(Hh[(size_t)s3 * 64 + lane]);
                float v4 = h2f(Hh[(size_t)s4 * 64 + lane]);
                float v5 = h2f(Hh[(size_t)s5 * 64 + lane]);
                float v6 = h2f(Hh[(size_t)s6 * 64 + lane]);
                float v7 = h2f(Hh[(size_t)s7 * 64 + lane]);
                a += ((v0 + v1) + (v2 + v3)) + ((v4 + v5) + (v6 + v7));
            }
            for (; i < e1; i++)
                a += h2f(Hh[(size_t)srt[i] * 64 + lane]);
            acc[q] = a;
        }
        __syncthreads();  // protect cnt/ew/srt reuse next chunk
    }
    float bv = b[lane];
#pragma unroll
    for (int q = 0; q < 32; q++) {
        int nl = wave * 32 + q;
        if (nl < nn) {
            int node = node0 + nl;
            float dv = dinv[node];
            float self = h2f(Hh[(size_t)node * 64 + lane]);  // already x dinv[node]
            float v = fmaxf(fmaf(acc[q] + self, dv, bv), 0.0f);
            if (F16OUT) ((unsigned short*)outv)[(size_t)node * 64 + lane] = f2h(v);
            else        ((float*)outv)[(size_t)node * 64 + lane] = v;
        }
    }
}

// ---- edge MLP via MFMA, direct global->register gather, no LDS -------------
__global__ __launch_bounds__(256, 3) void edge_mlp_direct_k(
    const unsigned short* __restrict__ hb, const float* __restrict__ attr,
    const int* __restrict__ src, const int* __restrict__ dst,
    const unsigned short* __restrict__ W1t,  // [64][168] fp16, transposed+padded
    const float* __restrict__ b1, const float* __restrict__ W2,
    const float* __restrict__ b2, float* __restrict__ out, int E, int nwaves) {
    int t = threadIdx.x;
    int lane = t & 63;
    int col = lane & 15;
    int quad = lane >> 4;
    int wid = blockIdx.x * 4 + (t >> 6);

    half8 Wf[4][5];
#pragma unroll
    for (int nt = 0; nt < 4; nt++)
#pragma unroll
        for (int kc = 0; kc < 5; kc++)
            Wf[nt][kc] = *(const half8*)&W1t[(nt * 16 + col) * 168 + kc * 32 + quad * 8];
    float b1v[4], w2v[4];
#pragma unroll
    for (int nt = 0; nt < 4; nt++) {
        b1v[nt] = b1[nt * 16 + col];
        w2v[nt] = W2[nt * 16 + col];
    }
    float b2v = b2[0];

    for (int base = wid * 32; base < E; base += nwaves * 32) {
        f32x4 acc[2][4];
#pragma unroll
        for (int mt = 0; mt < 2; mt++)
#pragma unroll
            for (int nt = 0; nt < 4; nt++)
                acc[mt][nt] = (f32x4){b1v[nt], b1v[nt], b1v[nt], b1v[nt]};
#pragma unroll
        for (int mt = 0; mt < 2; mt++) {
            int e = base + mt * 16 + col;
            e = e < E ? e : E - 1;
            int s = src[e], d = dst[e];
            half8 a0 = *(const half8*)&hb[(size_t)s * 64 + quad * 8];
            half8 a1 = *(const half8*)&hb[(size_t)s * 64 + 32 + quad * 8];
            half8 a2 = *(const half8*)&hb[(size_t)d * 64 + quad * 8];
            half8 a3 = *(const half8*)&hb[(size_t)d * 64 + 32 + quad * 8];
            half8 a4;
            if (quad == 0) {
                float4 x0 = ((const float4*)attr)[(size_t)e * 2];
                float4 x1 = ((const float4*)attr)[(size_t)e * 2 + 1];
                a4[0] = (_Float16)x0.x; a4[1] = (_Float16)x0.y;
                a4[2] = (_Float16)x0.z; a4[3] = (_Float16)x0.w;
                a4[4] = (_Float16)x1.x; a4[5] = (_Float16)x1.y;
                a4[6] = (_Float16)x1.z; a4[7] = (_Float16)x1.w;
            } else {
                a4 = (half8)(_Float16)0.0f;
            }
#pragma unroll
            for (int nt = 0; nt < 4; nt++) {
                acc[mt][nt] = __builtin_amdgcn_mfma_f32_16x16x32_f16(a0, Wf[nt][0], acc[mt][nt], 0, 0, 0);
                acc[mt][nt] = __builtin_amdgcn_mfma_f32_16x16x32_f16(a1, Wf[nt][1], acc[mt][nt], 0, 0, 0);
                acc[mt][nt] = __builtin_amdgcn_mfma_f32_16x16x32_f16(a2, Wf[nt][2], acc[mt][nt], 0, 0, 0);
                acc[mt][nt] = __builtin_amdgcn_mfma_f32_16x16x32_f16(a3, Wf[nt][3], acc[mt][nt], 0, 0, 0);
                acc[mt][nt] = __builtin_amdgcn_mfma_f32_16x16x32_f16(a4, Wf[nt][4], acc[mt][nt], 0, 0, 0);
            }
        }
#pragma unroll
        for (int mt = 0; mt < 2; mt++)
#pragma unroll
            for (int reg = 0; reg < 4; reg++) {
                float p = 0.0f;
#pragma unroll
                for (int nt = 0; nt < 4; nt++)
                    p = fmaf(fmaxf(acc[mt][nt][reg], 0.0f), w2v[nt], p);
                p += __shfl_xor(p, 1);
                p += __shfl_xor(p, 2);
                p += __shfl_xor(p, 4);
                p += __shfl_xor(p, 8);
                if (col == 0) {
                    int e = base + mt * 16 + quad * 4 + reg;
                    if (e < E) out[e] = p + b2v;
                }
            }
    }
}

extern "C" void kernel_launch(void* const* d_in, const int* in_sizes, int n_in,
                              void* d_out, int out_size, void* d_ws, size_t ws_size,
                              hipStream_t stream) {
    const float* x    = (const float*)d_in[0];
    const float* attr = (const float*)d_in[1];
    const float* W_e  = (const float*)d_in[2];
    const float* b_e  = (const float*)d_in[3];
    const float* W_c1 = (const float*)d_in[4];
    const float* b_c1 = (const float*)d_in[5];
    const float* W_c2 = (const float*)d_in[6];
    const float* b_c2 = (const float*)d_in[7];
    const float* W_p1 = (const float*)d_in[8];
    const float* b_p1 = (const float*)d_in[9];
    const float* W_p2 = (const float*)d_in[10];
    const float* b_p2 = (const float*)d_in[11];
    const void*  ei   = d_in[12];
    int N = in_sizes[0] / 32;
    int E = in_sizes[1] / 8;
    int n1 = N + 1;
    int nbkt = (N + RB - 1) / RB;
    float* out = (float*)d_out;

    char* p = (char*)d_ws;
    auto alloc = [&](size_t bytes) { void* q = p; p += (bytes + 255) & ~(size_t)255; return q; };
    float* A            = (float*)alloc((size_t)N * 64 * 4);   // h0; hb aliases later
    float* B            = (float*)alloc((size_t)N * 64 * 4);   // h1
    unsigned short* Hh  = (unsigned short*)alloc((size_t)N * 64 * 2);  // fp16 hW*dinv
    float* dinv         = (float*)alloc((size_t)N * 4);
    int* srcI           = (int*)alloc((size_t)E * 4);
    int* dstI           = (int*)alloc((size_t)E * 4);
    unsigned int* pairB = (unsigned int*)alloc((size_t)E * 4);
    int* deg            = (int*)alloc((size_t)n1 * 4);
    int* rowptr         = (int*)alloc((size_t)n1 * 4);
    int* part           = (int*)alloc((size_t)n1 * 4);
    int* bsum           = (int*)alloc(512 * 4);
    int* bcur           = (int*)alloc((size_t)nbkt * 4);
    unsigned short* W1t = (unsigned short*)alloc(64 * 168 * 2);
    int* flag           = (int*)alloc(4);
    unsigned short* hb = (unsigned short*)A;  // h0 dead after lin of conv2

    auto cdiv = [](long long a, long long b) { return (int)((a + b - 1) / b); };

    detect_idx_k<<<1, 64, 0, stream>>>((const unsigned int*)ei, flag);
    hipMemsetAsync(deg, 0, (size_t)n1 * 4, stream);
    cvt_deg_k<<<cdiv(2LL * E, 256), 256, 0, stream>>>(ei, flag, srcI, deg, E);
    int nb = cdiv(n1, 256);
    scan_blk_k<<<nb, 256, 0, stream>>>(deg, part, bsum, n1);
    scan_tot_k<<<1, 512, 0, stream>>>(bsum, nb);
    scan_add_k<<<nb, 256, 0, stream>>>(part, bsum, rowptr, n1);
    dinv_k<<<cdiv(N, 256), 256, 0, stream>>>(deg, dinv, N);
    bcur_init_k<<<cdiv(nbkt, 256), 256, 0, stream>>>(rowptr, bcur, nbkt);
    bin_k<<<cdiv(E, BINCHUNK), 256, 0, stream>>>(srcI, dstI, bcur, pairB, E, nbkt);
    prep_w1_k<<<cdiv(64 * 168, 256), 256, 0, stream>>>(W_p1, W1t);
    // network
    int lg = cdiv(N, 128);
    lin_tile_k<32, true, true, false, false><<<lg, 256, 0, stream>>>(x, W_e, b_e, nullptr, A, N);
    lin_tile_k<64, false, false, true, true><<<lg, 256, 0, stream>>>(A, W_c1, nullptr, dinv, Hh, N);
    conv_sorted_k<false><<<nbkt, 256, 0, stream>>>(Hh, dinv, rowptr, pairB, b_c1, B, N);
    lin_tile_k<64, false, false, true, true><<<lg, 256, 0, stream>>>(B, W_c2, nullptr, dinv, Hh, N);
    conv_sorted_k<true><<<nbkt, 256, 0, stream>>>(Hh, dinv, rowptr, pairB, b_c2, hb, N);
    const int NB = 768;
    edge_mlp_direct_k<<<NB, 256, 0, stream>>>(hb, attr, srcI, dstI, W1t,
                                              b_p1, W_p2, b_p2, out, E, NB * 4);
}

// Round 9
// 525.175 us; speedup vs baseline: 3.4131x; 1.2745x over previous
//
#include <hip/hip_runtime.h>
#include <hip/hip_fp16.h>

// ---------------------------------------------------------------------------
// GNN traffic predictor: embed -> GCNConv x2 -> edge MLP
// N=100000, E=1600000, F_NODE=32, F_EDGE=8, H=64
// Round 9: split sort from gather. Round-8 fused sort+gather at grid=782
// blocks (3/CU) was TLP-starved (VALUBusy 15%, occ 30%, 143us). Now:
// sortb_k materializes node-sorted srcS ONCE (per-bucket LDS counting sort,
// coalesced write-out), and conv is round-5's wave-per-node register gather
// (grid 25000 blocks) minus the per-edge dinv gather (Hh pre-scaled).
// ---------------------------------------------------------------------------

typedef __attribute__((ext_vector_type(8))) _Float16 half8;
typedef __attribute__((ext_vector_type(4))) float f32x4;

__device__ __forceinline__ unsigned short f2h(float f) {
    return __half_as_ushort(__float2half(f));
}
__device__ __forceinline__ float h2f(unsigned short u) {
    return __half2float(__ushort_as_half(u));
}

#define RB 128           // nodes per bucket
#define NBKT 782         // ceil(100000/128); recomputed at launch
#define BINCHUNK 4096    // edges per bin_k block
#define SCH 4096         // sortb in-LDS capacity (edges per bucket)

// ---- index dtype detection: flag=1 -> int32, 0 -> int64 --------------------
__global__ void detect_idx_k(const unsigned int* __restrict__ ei, int* __restrict__ flag) {
    int nz = 0;
    for (int i = threadIdx.x; i < 2048; i += 64)
        if (ei[2 * i + 1] != 0u) nz = 1;
    unsigned long long m = __ballot(nz);
    if (threadIdx.x == 0) *flag = (m != 0ull) ? 1 : 0;
}

// ---- fused index convert + degree count ------------------------------------
__global__ void cvt_deg_k(const void* __restrict__ ei, const int* __restrict__ flag,
                          int* __restrict__ out, int* __restrict__ deg, int E) {
    int i = blockIdx.x * 256 + threadIdx.x;
    if (i >= 2 * E) return;
    int v;
    if (*flag) v = ((const int*)ei)[i];
    else       v = (int)((const long long*)ei)[i];
    out[i] = v;
    if (i >= E) atomicAdd(&deg[v], 1);  // dst half
}

// ---- rowptr scan -----------------------------------------------------------
__global__ void scan_blk_k(const int* __restrict__ deg, int* __restrict__ part,
                           int* __restrict__ bsum, int n1) {
    __shared__ int s[256];
    int t = threadIdx.x;
    int i = blockIdx.x * 256 + t;
    int v = (i < n1) ? deg[i] : 0;
    s[t] = v;
    __syncthreads();
    for (int o = 1; o < 256; o <<= 1) {
        int x = (t >= o) ? s[t - o] : 0;
        __syncthreads();
        s[t] += x;
        __syncthreads();
    }
    if (i < n1) part[i] = s[t] - v;  // exclusive
    if (t == 255) bsum[blockIdx.x] = s[255];
}

__global__ void scan_tot_k(int* __restrict__ bsum, int nb) {
    __shared__ int s[512];
    int t = threadIdx.x;
    int v = (t < nb) ? bsum[t] : 0;
    s[t] = v;
    __syncthreads();
    for (int o = 1; o < 512; o <<= 1) {
        int x = (t >= o) ? s[t - o] : 0;
        __syncthreads();
        s[t] += x;
        __syncthreads();
    }
    if (t < nb) bsum[t] = s[t] - v;
}

__global__ void scan_add_k(const int* __restrict__ part, const int* __restrict__ bsum,
                           int* __restrict__ rowptr, int n1) {
    int i = blockIdx.x * 256 + threadIdx.x;
    if (i < n1) rowptr[i] = part[i] + bsum[blockIdx.x];
}

__global__ void dinv_k(const int* __restrict__ deg, float* __restrict__ dinv, int n) {
    int i = blockIdx.x * 256 + threadIdx.x;
    if (i < n) dinv[i] = rsqrtf((float)deg[i] + 1.0f);  // +1 self-loop
}

__global__ void bcur_init_k(const int* __restrict__ rowptr, int* __restrict__ bcur,
                            int nbkt) {
    int b = blockIdx.x * 256 + threadIdx.x;
    if (b < nbkt) bcur[b] = rowptr[b * RB];
}

// ---- bucket binning: pairB[slot] = src | (dst&127)<<20, grouped by dst>>7 --
__global__ __launch_bounds__(256) void bin_k(
    const int* __restrict__ src, const int* __restrict__ dst,
    int* __restrict__ bcur, unsigned int* __restrict__ pairB, int E, int nbkt) {
    __shared__ int lsrc[BINCHUNK];
    __shared__ int ldst[BINCHUNK];
    __shared__ int cnt[NBKT], gbase[NBKT];
    int t = threadIdx.x;
    int base = blockIdx.x * BINCHUNK;
    int n = E - base; if (n > BINCHUNK) n = BINCHUNK;
    for (int i = t; i < nbkt; i += 256) cnt[i] = 0;
    for (int i = t; i < n; i += 256) {
        lsrc[i] = src[base + i];
        ldst[i] = dst[base + i];
    }
    __syncthreads();
    int rank[BINCHUNK / 256];
#pragma unroll
    for (int j = 0; j < BINCHUNK / 256; j++) {
        int i = t + j * 256;
        if (i < n) rank[j] = atomicAdd(&cnt[ldst[i] >> 7], 1);
    }
    __syncthreads();
    for (int b = t; b < nbkt; b += 256)
        if (cnt[b] > 0) gbase[b] = atomicAdd(&bcur[b], cnt[b]);
    __syncthreads();
#pragma unroll
    for (int j = 0; j < BINCHUNK / 256; j++) {
        int i = t + j * 256;
        if (i < n) {
            int d = ldst[i];
            unsigned w = (unsigned)lsrc[i] | ((unsigned)(d & (RB - 1)) << 20);
            pairB[gbase[d >> 7] + rank[j]] = w;
        }
    }
}

// ---- one-shot node-sort: pairB (bucket-grouped) -> srcS (node-sorted) ------
// Bucket <= SCH: in-LDS counting sort + fully coalesced write-out.
// Bigger buckets (rare): LDS cursor scatter (correct, slower).
__global__ __launch_bounds__(256) void sortb_k(
    const int* __restrict__ rowptr, const unsigned int* __restrict__ pairB,
    int* __restrict__ srcS, int N) {
    __shared__ unsigned int ew[SCH];
    __shared__ int srt[SCH];
    __shared__ int cnt[RB], sc[RB], cur[RB];
    int t = threadIdx.x;
    int node0 = blockIdx.x * RB;
    int nn = N - node0; if (nn > RB) nn = RB;
    int beg = rowptr[node0], end = rowptr[node0 + nn];
    int bn = end - beg;
    if (bn <= SCH) {
        if (t < RB) cnt[t] = 0;
        __syncthreads();
        for (int i = t; i < bn; i += 256) {
            unsigned w = pairB[beg + i];
            ew[i] = w;
            atomicAdd(&cnt[w >> 20], 1);  // f&f int ds_add
        }
        __syncthreads();
        if (t < RB) sc[t] = cnt[t];
        __syncthreads();
        for (int o = 1; o < RB; o <<= 1) {
            int v = 0;
            if (t < RB && t >= o) v = sc[t - o];
            __syncthreads();
            if (t < RB) sc[t] += v;
            __syncthreads();
        }
        if (t < RB) cur[t] = sc[t] - cnt[t];
        __syncthreads();
        for (int i = t; i < bn; i += 256) {
            unsigned w = ew[i];
            int r = atomicAdd(&cur[w >> 20], 1);
            srt[r] = (int)(w & 0xFFFFF);
        }
        __syncthreads();
        for (int i = t; i < bn; i += 256)
            srcS[beg + i] = srt[i];  // coalesced
    } else {
        if (t < nn) cur[t] = rowptr[node0 + t];  // global cursors
        __syncthreads();
        for (int i = t; i < bn; i += 256) {
            unsigned w = pairB[beg + i];
            int r = atomicAdd(&cur[w >> 20], 1);
            srcS[r] = (int)(w & 0xFFFFF);
        }
    }
}

// ---- W1 -> fp16 transposed, padded [64][168], zero K-tail ------------------
__global__ void prep_w1_k(const float* __restrict__ W1, unsigned short* __restrict__ W1t) {
    int i = blockIdx.x * 256 + threadIdx.x;
    if (i >= 64 * 168) return;
    int n = i / 168, k = i % 168;
    float v = (k < 136) ? W1[k * 64 + n] : 0.0f;
    W1t[i] = f2h(v);
}

// ---- register-tiled GEMM: C[n,64] = act(A[n,K] @ W[K,64] (+b)) (x dinv) ----
template <int K, bool BIAS, bool RELU, bool F16OUT, bool DINV>
__global__ __launch_bounds__(256, 4) void lin_tile_k(
    const float* __restrict__ A, const float* __restrict__ W,
    const float* __restrict__ b, const float* __restrict__ dinv,
    void* __restrict__ outv, int n) {
    constexpr int KP = K + 4;
    __shared__ float As[128 * KP];
    __shared__ float Ws[64 * KP];
    int t = threadIdx.x;
    constexpr int K4 = K / 4;
    for (int i = t; i < 128 * K4; i += 256) {
        int r = i / K4, c4 = i % K4;
        int row = blockIdx.x * 128 + r;
        row = row < n ? row : n - 1;
        *(float4*)&As[r * KP + c4 * 4] = *(const float4*)&A[(size_t)row * K + c4 * 4];
    }
    for (int i = t; i < K * 64; i += 256) {
        int k = i >> 6, j = i & 63;
        Ws[j * KP + k] = W[i];
    }
    __syncthreads();
    int lane = t & 63;
    int wave = t >> 6;
    int ri = lane >> 3, ji = lane & 7;
    float acc[4][8];
#pragma unroll
    for (int m = 0; m < 4; m++)
#pragma unroll
        for (int c = 0; c < 8; c++) acc[m][c] = BIAS ? b[ji + 8 * c] : 0.0f;
#pragma unroll 2
    for (int kc = 0; kc < K; kc += 4) {
        float4 a[4], w[8];
#pragma unroll
        for (int m = 0; m < 4; m++)
            a[m] = *(const float4*)&As[(wave * 32 + ri + 8 * m) * KP + kc];
#pragma unroll
        for (int c = 0; c < 8; c++)
            w[c] = *(const float4*)&Ws[(ji + 8 * c) * KP + kc];
#pragma unroll
        for (int m = 0; m < 4; m++)
#pragma unroll
            for (int c = 0; c < 8; c++) {
                acc[m][c] = fmaf(a[m].x, w[c].x, acc[m][c]);
                acc[m][c] = fmaf(a[m].y, w[c].y, acc[m][c]);
                acc[m][c] = fmaf(a[m].z, w[c].z, acc[m][c]);
                acc[m][c] = fmaf(a[m].w, w[c].w, acc[m][c]);
            }
    }
#pragma unroll
    for (int m = 0; m < 4; m++) {
        int row = blockIdx.x * 128 + wave * 32 + ri + 8 * m;
        if (row < n) {
            float dv = DINV ? dinv[row] : 1.0f;
#pragma unroll
            for (int c = 0; c < 8; c++) {
                float v = acc[m][c];
                if (RELU) v = fmaxf(v, 0.0f);
                if (DINV) v *= dv;
                if (F16OUT) ((unsigned short*)outv)[(size_t)row * 64 + ji + 8 * c] = f2h(v);
                else        ((float*)outv)[(size_t)row * 64 + ji + 8 * c] = v;
            }
        }
    }
}

// ---- conv gather: wave per node over node-sorted srcS ----------------------
// out[d] = relu((sum_e Hh[srcS[e]] + Hh[d]) * dinv[d] + b); Hh pre-scaled by
// dinv[src]. Grid N/4 blocks (~98/CU) hides scattered-row latency with TLP.
template <bool F16OUT>
__global__ __launch_bounds__(256) void conv_gather2_k(
    const unsigned short* __restrict__ Hh, const float* __restrict__ dinv,
    const int* __restrict__ rowptr, const int* __restrict__ srcS,
    const float* __restrict__ b, void* __restrict__ outv, int N) {
    int lane = threadIdx.x & 63;
    int wave = threadIdx.x >> 6;
    int node = blockIdx.x * 4 + wave;
    if (node >= N) return;
    int beg = rowptr[node], end = rowptr[node + 1];
    float acc = h2f(Hh[(size_t)node * 64 + lane]);  // self-loop (pre-scaled)
    int i = beg;
    for (; i + 8 <= end; i += 8) {
        int s0 = srcS[i], s1 = srcS[i + 1], s2 = srcS[i + 2], s3 = srcS[i + 3];
        int s4 = srcS[i + 4], s5 = srcS[i + 5], s6 = srcS[i + 6], s7 = srcS[i + 7];
        float v0 = h2f(Hh[(size_t)s0 * 64 + lane]);
        float v1 = h2f(Hh[(size_t)s1 * 64 + lane]);
        float v2 = h2f(Hh[(size_t)s2 * 64 + lane]);
        float v3 = h2f(Hh[(size_t)s3 * 64 + lane]);
        float v4 = h2f(Hh[(size_t)s4 * 64 + lane]);
        float v5 = h2f(Hh[(size_t)s5 * 64 + lane]);
        float v6 = h2f(Hh[(size_t)s6 * 64 + lane]);
        float v7 = h2f(Hh[(size_t)s7 * 64 + lane]);
        acc += ((v0 + v1) + (v2 + v3)) + ((v4 + v5) + (v6 + v7));
    }
    for (; i < end; i++)
        acc += h2f(Hh[(size_t)srcS[i] * 64 + lane]);
    float v = fmaxf(fmaf(acc, dinv[node], b[lane]), 0.0f);
    if (F16OUT) ((unsigned short*)outv)[(size_t)node * 64 + lane] = f2h(v);
    else        ((float*)outv)[(size_t)node * 64 + lane] = v;
}

// ---- edge MLP via MFMA, direct global->register gather, no LDS -------------
__global__ __launch_bounds__(256, 3) void edge_mlp_direct_k(
    const unsigned short* __restrict__ hb, const float* __restrict__ attr,
    const int* __restrict__ src, const int* __restrict__ dst,
    const unsigned short* __restrict__ W1t,  // [64][168] fp16, transposed+padded
    const float* __restrict__ b1, const float* __restrict__ W2,
    const float* __restrict__ b2, float* __restrict__ out, int E, int nwaves) {
    int t = threadIdx.x;
    int lane = t & 63;
    int col = lane & 15;
    int quad = lane >> 4;
    int wid = blockIdx.x * 4 + (t >> 6);

    half8 Wf[4][5];
#pragma unroll
    for (int nt = 0; nt < 4; nt++)
#pragma unroll
        for (int kc = 0; kc < 5; kc++)
            Wf[nt][kc] = *(const half8*)&W1t[(nt * 16 + col) * 168 + kc * 32 + quad * 8];
    float b1v[4], w2v[4];
#pragma unroll
    for (int nt = 0; nt < 4; nt++) {
        b1v[nt] = b1[nt * 16 + col];
        w2v[nt] = W2[nt * 16 + col];
    }
    float b2v = b2[0];

    for (int base = wid * 32; base < E; base += nwaves * 32) {
        f32x4 acc[2][4];
#pragma unroll
        for (int mt = 0; mt < 2; mt++)
#pragma unroll
            for (int nt = 0; nt < 4; nt++)
                acc[mt][nt] = (f32x4){b1v[nt], b1v[nt], b1v[nt], b1v[nt]};
#pragma unroll
        for (int mt = 0; mt < 2; mt++) {
            int e = base + mt * 16 + col;
            e = e < E ? e : E - 1;
            int s = src[e], d = dst[e];
            half8 a0 = *(const half8*)&hb[(size_t)s * 64 + quad * 8];
            half8 a1 = *(const half8*)&hb[(size_t)s * 64 + 32 + quad * 8];
            half8 a2 = *(const half8*)&hb[(size_t)d * 64 + quad * 8];
            half8 a3 = *(const half8*)&hb[(size_t)d * 64 + 32 + quad * 8];
            half8 a4;
            if (quad == 0) {
                float4 x0 = ((const float4*)attr)[(size_t)e * 2];
                float4 x1 = ((const float4*)attr)[(size_t)e * 2 + 1];
                a4[0] = (_Float16)x0.x; a4[1] = (_Float16)x0.y;
                a4[2] = (_Float16)x0.z; a4[3] = (_Float16)x0.w;
                a4[4] = (_Float16)x1.x; a4[5] = (_Float16)x1.y;
                a4[6] = (_Float16)x1.z; a4[7] = (_Float16)x1.w;
            } else {
                a4 = (half8)(_Float16)0.0f;
            }
#pragma unroll
            for (int nt = 0; nt < 4; nt++) {
                acc[mt][nt] = __builtin_amdgcn_mfma_f32_16x16x32_f16(a0, Wf[nt][0], acc[mt][nt], 0, 0, 0);
                acc[mt][nt] = __builtin_amdgcn_mfma_f32_16x16x32_f16(a1, Wf[nt][1], acc[mt][nt], 0, 0, 0);
                acc[mt][nt] = __builtin_amdgcn_mfma_f32_16x16x32_f16(a2, Wf[nt][2], acc[mt][nt], 0, 0, 0);
                acc[mt][nt] = __builtin_amdgcn_mfma_f32_16x16x32_f16(a3, Wf[nt][3], acc[mt][nt], 0, 0, 0);
                acc[mt][nt] = __builtin_amdgcn_mfma_f32_16x16x32_f16(a4, Wf[nt][4], acc[mt][nt], 0, 0, 0);
            }
        }
#pragma unroll
        for (int mt = 0; mt < 2; mt++)
#pragma unroll
            for (int reg = 0; reg < 4; reg++) {
                float p = 0.0f;
#pragma unroll
                for (int nt = 0; nt < 4; nt++)
                    p = fmaf(fmaxf(acc[mt][nt][reg], 0.0f), w2v[nt], p);
                p += __shfl_xor(p, 1);
                p += __shfl_xor(p, 2);
                p += __shfl_xor(p, 4);
                p += __shfl_xor(p, 8);
                if (col == 0) {
                    int e = base + mt * 16 + quad * 4 + reg;
                    if (e < E) out[e] = p + b2v;
                }
            }
    }
}

extern "C" void kernel_launch(void* const* d_in, const int* in_sizes, int n_in,
                              void* d_out, int out_size, void* d_ws, size_t ws_size,
                              hipStream_t stream) {
    const float* x    = (const float*)d_in[0];
    const float* attr = (const float*)d_in[1];
    const float* W_e  = (const float*)d_in[2];
    const float* b_e  = (const float*)d_in[3];
    const float* W_c1 = (const float*)d_in[4];
    const float* b_c1 = (const float*)d_in[5];
    const float* W_c2 = (const float*)d_in[6];
    const float* b_c2 = (const float*)d_in[7];
    const float* W_p1 = (const float*)d_in[8];
    const float* b_p1 = (const float*)d_in[9];
    const float* W_p2 = (const float*)d_in[10];
    const float* b_p2 = (const float*)d_in[11];
    const void*  ei   = d_in[12];
    int N = in_sizes[0] / 32;
    int E = in_sizes[1] / 8;
    int n1 = N + 1;
    int nbkt = (N + RB - 1) / RB;
    float* out = (float*)d_out;

    char* p = (char*)d_ws;
    auto alloc = [&](size_t bytes) { void* q = p; p += (bytes + 255) & ~(size_t)255; return q; };
    float* A            = (float*)alloc((size_t)N * 64 * 4);   // h0; hb aliases later
    float* B            = (float*)alloc((size_t)N * 64 * 4);   // h1
    unsigned short* Hh  = (unsigned short*)alloc((size_t)N * 64 * 2);  // fp16 hW*dinv
    float* dinv         = (float*)alloc((size_t)N * 4);
    int* srcI           = (int*)alloc((size_t)E * 4);
    int* dstI           = (int*)alloc((size_t)E * 4);
    unsigned int* pairB = (unsigned int*)alloc((size_t)E * 4);
    int* srcS           = (int*)alloc((size_t)E * 4);
    int* deg            = (int*)alloc((size_t)n1 * 4);
    int* rowptr         = (int*)alloc((size_t)n1 * 4);
    int* part           = (int*)alloc((size_t)n1 * 4);
    int* bsum           = (int*)alloc(512 * 4);
    int* bcur           = (int*)alloc((size_t)nbkt * 4);
    unsigned short* W1t = (unsigned short*)alloc(64 * 168 * 2);
    int* flag           = (int*)alloc(4);
    unsigned short* hb = (unsigned short*)A;  // h0 dead after lin of conv2

    auto cdiv = [](long long a, long long b) { return (int)((a + b - 1) / b); };

    detect_idx_k<<<1, 64, 0, stream>>>((const unsigned int*)ei, flag);
    hipMemsetAsync(deg, 0, (size_t)n1 * 4, stream);
    cvt_deg_k<<<cdiv(2LL * E, 256), 256, 0, stream>>>(ei, flag, srcI, deg, E);
    int nb = cdiv(n1, 256);
    scan_blk_k<<<nb, 256, 0, stream>>>(deg, part, bsum, n1);
    scan_tot_k<<<1, 512, 0, stream>>>(bsum, nb);
    scan_add_k<<<nb, 256, 0, stream>>>(part, bsum, rowptr, n1);
    dinv_k<<<cdiv(N, 256), 256, 0, stream>>>(deg, dinv, N);
    bcur_init_k<<<cdiv(nbkt, 256), 256, 0, stream>>>(rowptr, bcur, nbkt);
    bin_k<<<cdiv(E, BINCHUNK), 256, 0, stream>>>(srcI, dstI, bcur, pairB, E, nbkt);
    sortb_k<<<nbkt, 256, 0, stream>>>(rowptr, pairB, srcS, N);
    prep_w1_k<<<cdiv(64 * 168, 256), 256, 0, stream>>>(W_p1, W1t);
    // network
    int lg = cdiv(N, 128);
    lin_tile_k<32, true, true, false, false><<<lg, 256, 0, stream>>>(x, W_e, b_e, nullptr, A, N);
    lin_tile_k<64, false, false, true, true><<<lg, 256, 0, stream>>>(A, W_c1, nullptr, dinv, Hh, N);
    conv_gather2_k<false><<<cdiv(N, 4), 256, 0, stream>>>(Hh, dinv, rowptr, srcS, b_c1, B, N);
    lin_tile_k<64, false, false, true, true><<<lg, 256, 0, stream>>>(B, W_c2, nullptr, dinv, Hh, N);
    conv_gather2_k<true><<<cdiv(N, 4), 256, 0, stream>>>(Hh, dinv, rowptr, srcS, b_c2, hb, N);
    const int NB = 768;
    edge_mlp_direct_k<<<NB, 256, 0, stream>>>(hb, attr, srcI, dstI, W1t,
                                              b_p1, W_p2, b_p2, out, E, NB * 4);
}